// Round 1
// baseline (74.842 us; speedup 1.0000x reference)
//
#include <hip/hip_runtime.h>
#include <math.h>

// ws layout (floats): [0..639] k_eff (10 heads x 64), byte 2560: 10 x u64 packed argmax cells
#define PACK_OFF 640

__device__ __forceinline__ unsigned int fkey(float f) {
  unsigned int u = __float_as_uint(f);
  return (u & 0x80000000u) ? ~u : (u | 0x80000000u);
}
__device__ __forceinline__ float funkey(unsigned int k) {
  unsigned int u = (k & 0x80000000u) ? (k & 0x7fffffffu) : ~k;
  return __uint_as_float(u);
}

// ---- kernel 1: q = WQ@query + bQ ; k_eff[h] = q[h,0]*WK[h,0] + q[h,1]*WK[h,1]; zero atomics
__global__ void prep_kernel(const float* __restrict__ query,
                            const float* __restrict__ WQ,
                            const float* __restrict__ bQ,
                            const float* __restrict__ WK,
                            float* __restrict__ ws) {
  __shared__ float q[20];
  int tid = threadIdx.x;
  if (tid < 20) {
    const float* w = WQ + tid * 64;   // WQ[h][t][:] with tid = h*2+t
    float s = bQ[tid];
    for (int d = 0; d < 64; ++d) s += w[d] * query[d];
    q[tid] = s;
  }
  __syncthreads();
  for (int i = tid; i < 640; i += 256) {
    int h = i >> 6, d = i & 63;
    ws[i] = q[h * 2] * WK[h * 128 + d] + q[h * 2 + 1] * WK[h * 128 + 64 + d];
  }
  if (tid < 10) ((unsigned long long*)(ws + PACK_OFF))[tid] = 0ull;
}

// ---- kernel 2: scan all banks, per-head argmax via packed atomicMax
__global__ __launch_bounds__(256) void scan_kernel(
    const float* __restrict__ prog, const float* __restrict__ stck,
    const float* __restrict__ locl, const float* __restrict__ heap,
    const float* __restrict__ call, float* __restrict__ ws) {
  const float* keff = ws;
  unsigned long long* packed = (unsigned long long*)(ws + PACK_OFF);

  int b = blockIdx.x;
  const float* mem; int nrows, h0, nh, brank, nblocks;
  if (b < 512)       { mem = prog; nrows = 262144; h0 = 0; nh = 2; brank = b;        nblocks = 512; }
  else if (b < 768)  { mem = stck; nrows = 131072; h0 = 2; nh = 3; brank = b - 512;  nblocks = 256; }
  else if (b < 1024) { mem = locl; nrows = 131072; h0 = 5; nh = 2; brank = b - 768;  nblocks = 256; }
  else if (b < 1536) { mem = heap; nrows = 262144; h0 = 7; nh = 2; brank = b - 1024; nblocks = 512; }
  else               { mem = call; nrows = 32768;  h0 = 9; nh = 1; brank = b - 1536; nblocks = 64;  }

  int tid = threadIdx.x;
  int lane16 = tid & 15;   // position within a row (4 floats each)
  int rsub = tid >> 4;     // which of 16 rows this block-iteration

  float4 z = make_float4(0.f, 0.f, 0.f, 0.f);
  float4 k0 = *(const float4*)(keff + h0 * 64 + lane16 * 4);
  float4 k1 = (nh > 1) ? *(const float4*)(keff + (h0 + 1) * 64 + lane16 * 4) : z;
  float4 k2 = (nh > 2) ? *(const float4*)(keff + (h0 + 2) * 64 + lane16 * 4) : z;

  float bs0 = -INFINITY, bs1 = -INFINITY, bs2 = -INFINITY;
  int bi0 = 0, bi1 = 0, bi2 = 0;

  int stride = nblocks * 16;
  for (int r = brank * 16 + rsub; r < nrows; r += stride) {
    float4 v = *(const float4*)(mem + (size_t)r * 64 + (lane16 << 2));
    float s0 = v.x * k0.x + v.y * k0.y + v.z * k0.z + v.w * k0.w;
    float s1 = v.x * k1.x + v.y * k1.y + v.z * k1.z + v.w * k1.w;
    float s2 = v.x * k2.x + v.y * k2.y + v.z * k2.z + v.w * k2.w;
#pragma unroll
    for (int m = 1; m < 16; m <<= 1) {
      s0 += __shfl_xor(s0, m);
      s1 += __shfl_xor(s1, m);
      s2 += __shfl_xor(s2, m);
    }
    if (s0 > bs0) { bs0 = s0; bi0 = r; }
    if (s1 > bs1) { bs1 = s1; bi1 = r; }
    if (s2 > bs2) { bs2 = s2; bi2 = r; }
  }

  // pack: high 32 = sortable score key, low 32 = ~idx (ties -> smallest idx wins max)
  unsigned long long p0 = ((unsigned long long)fkey(bs0) << 32) | (unsigned long long)(0xFFFFFFFFu - (unsigned)bi0);
  unsigned long long p1 = ((unsigned long long)fkey(bs1) << 32) | (unsigned long long)(0xFFFFFFFFu - (unsigned)bi1);
  unsigned long long p2 = ((unsigned long long)fkey(bs2) << 32) | (unsigned long long)(0xFFFFFFFFu - (unsigned)bi2);
#pragma unroll
  for (int m = 1; m < 64; m <<= 1) {
    unsigned long long t;
    t = __shfl_xor(p0, m); if (t > p0) p0 = t;
    t = __shfl_xor(p1, m); if (t > p1) p1 = t;
    t = __shfl_xor(p2, m); if (t > p2) p2 = t;
  }
  __shared__ unsigned long long red[3][4];
  int wv = tid >> 6;
  if ((tid & 63) == 0) { red[0][wv] = p0; red[1][wv] = p1; red[2][wv] = p2; }
  __syncthreads();
  if (tid == 0) {
#pragma unroll
    for (int h = 0; h < 3; ++h) {
      if (h >= nh) break;
      unsigned long long m0 = red[h][0];
      for (int w = 1; w < 4; ++w) if (red[h][w] > m0) m0 = red[h][w];
      atomicMax(&packed[h0 + h], m0);
    }
  }
}

// ---- kernel 3: decode winners, compute 12 value dots, write all 32 outputs
__global__ void epi_kernel(const float* __restrict__ prog, const float* __restrict__ stck,
                           const float* __restrict__ locl, const float* __restrict__ heap,
                           const float* __restrict__ call,
                           const float* __restrict__ WV1, const float* __restrict__ WVc,
                           const float* __restrict__ ws, float* __restrict__ out) {
  const unsigned long long* packed = (const unsigned long long*)(ws + PACK_OFF);
  __shared__ int sidx[10];
  int tid = threadIdx.x;
  if (tid < 10) {
    unsigned long long p = packed[tid];
    unsigned int key = (unsigned int)(p >> 32);
    int idx = (int)(0xFFFFFFFFu - (unsigned int)(p & 0xFFFFFFFFull));
    sidx[tid] = idx;
    out[12 + tid] = funkey(key);        // best_scores
    out[22 + tid] = (float)idx;         // best_idx (as f32)
  }
  __syncthreads();
  int p = tid >> 4, l = tid & 15;
  if (p < 12) {
    int hh = (p < 9) ? p : 9;
    const float* wrow = (p < 9) ? (WV1 + p * 64) : (WVc + (p - 9) * 64);
    const float* mem;
    if (hh < 2) mem = prog;
    else if (hh < 5) mem = stck;
    else if (hh < 7) mem = locl;
    else if (hh < 9) mem = heap;
    else mem = call;
    const float* row = mem + (size_t)sidx[hh] * 64;
    float s = 0.f;
#pragma unroll
    for (int j = 0; j < 4; ++j) s += wrow[l * 4 + j] * row[l * 4 + j];
#pragma unroll
    for (int m = 1; m < 16; m <<= 1) s += __shfl_xor(s, m);
    if (l == 0) out[p] = s;
  }
}

extern "C" void kernel_launch(void* const* d_in, const int* in_sizes, int n_in,
                              void* d_out, int out_size, void* d_ws, size_t ws_size,
                              hipStream_t stream) {
  const float* query = (const float*)d_in[0];
  const float* prog  = (const float*)d_in[1];
  const float* stck  = (const float*)d_in[2];
  const float* locl  = (const float*)d_in[3];
  const float* heap  = (const float*)d_in[4];
  const float* call  = (const float*)d_in[5];
  const float* WQ    = (const float*)d_in[6];
  const float* bQ    = (const float*)d_in[7];
  const float* WK    = (const float*)d_in[8];
  const float* WV1   = (const float*)d_in[9];
  const float* WVc   = (const float*)d_in[10];
  float* ws  = (float*)d_ws;
  float* out = (float*)d_out;

  hipLaunchKernelGGL(prep_kernel, dim3(1), dim3(256), 0, stream, query, WQ, bQ, WK, ws);
  hipLaunchKernelGGL(scan_kernel, dim3(1600), dim3(256), 0, stream,
                     prog, stck, locl, heap, call, ws);
  hipLaunchKernelGGL(epi_kernel, dim3(1), dim3(256), 0, stream,
                     prog, stck, locl, heap, call, WV1, WVc, ws, out);
}

// Round 2
// 63.267 us; speedup vs baseline: 1.1829x; 1.1829x over previous
//
#include <hip/hip_runtime.h>
#include <math.h>

// ws layout (floats): [0..639] k_eff (10 heads x 64); byte 2560: 10 x u64 packed argmax cells
#define PACK_OFF 640

__device__ __forceinline__ unsigned int fkey(float f) {
  unsigned int u = __float_as_uint(f);
  return (u & 0x80000000u) ? ~u : (u | 0x80000000u);
}
__device__ __forceinline__ float funkey(unsigned int k) {
  unsigned int u = (k & 0x80000000u) ? (k & 0x7fffffffu) : ~k;
  return __uint_as_float(u);
}
__device__ __forceinline__ float dot4(float4 a, float4 b) {
  return a.x * b.x + a.y * b.y + a.z * b.z + a.w * b.w;
}

// ---- kernel 1: q = WQ@query + bQ ; k_eff[h] = q[h,0]*WK[h,0] + q[h,1]*WK[h,1]; zero atomics
__global__ void prep_kernel(const float* __restrict__ query,
                            const float* __restrict__ WQ,
                            const float* __restrict__ bQ,
                            const float* __restrict__ WK,
                            float* __restrict__ ws) {
  __shared__ float q[20];
  int tid = threadIdx.x;
  if (tid < 20) {
    const float* w = WQ + tid * 64;   // WQ[h][t][:] with tid = h*2+t
    float s = bQ[tid];
    for (int d = 0; d < 64; ++d) s += w[d] * query[d];
    q[tid] = s;
  }
  __syncthreads();
  for (int i = tid; i < 640; i += 256) {
    int h = i >> 6, d = i & 63;
    ws[i] = q[h * 2] * WK[h * 128 + d] + q[h * 2 + 1] * WK[h * 128 + 64 + d];
  }
  if (tid < 10) ((unsigned long long*)(ws + PACK_OFF))[tid] = 0ull;
}

// ---- kernel 2: scan all banks; 4 lanes per row, 4 float4 loads in flight per lane,
//      2-stage shfl reduce; per-head argmax via packed atomicMax
__global__ __launch_bounds__(256) void scan_kernel(
    const float* __restrict__ prog, const float* __restrict__ stck,
    const float* __restrict__ locl, const float* __restrict__ heap,
    const float* __restrict__ call, float* __restrict__ ws) {
  const float* keff = ws;
  unsigned long long* packed = (unsigned long long*)(ws + PACK_OFF);

  int b = blockIdx.x;
  const float* mem; int h0, nh, brank;
  if (b < 512)       { mem = prog; h0 = 0; nh = 2; brank = b;        }
  else if (b < 768)  { mem = stck; h0 = 2; nh = 3; brank = b - 512;  }
  else if (b < 1024) { mem = locl; h0 = 5; nh = 2; brank = b - 768;  }
  else if (b < 1536) { mem = heap; h0 = 7; nh = 2; brank = b - 1024; }
  else               { mem = call; h0 = 9; nh = 1; brank = b - 1536; }
  // every block: contiguous 512-row chunk, 8 iterations x 64 rows

  int tid = threadIdx.x;
  int lane4 = tid & 3;     // column group: 16 consecutive floats
  int rsub = tid >> 2;     // row within 64-row sub-chunk

  float4 z = make_float4(0.f, 0.f, 0.f, 0.f);
  float4 ka[4], kb[4], kc[4];
#pragma unroll
  for (int j = 0; j < 4; ++j) {
    ka[j] = ((const float4*)(keff + (h0 + 0) * 64 + lane4 * 16))[j];
    kb[j] = (nh > 1) ? ((const float4*)(keff + (h0 + 1) * 64 + lane4 * 16))[j] : z;
    kc[j] = (nh > 2) ? ((const float4*)(keff + (h0 + 2) * 64 + lane4 * 16))[j] : z;
  }

  float bsA = -INFINITY, bsB = -INFINITY, bsC = -INFINITY;
  int biA = 0, biB = 0, biC = 0;

  int base = brank * 512;
#pragma unroll 2
  for (int it = 0; it < 8; ++it) {
    int r = base + it * 64 + rsub;
    const float4* rowp = (const float4*)(mem + (size_t)r * 64 + lane4 * 16);
    float4 v0 = rowp[0];
    float4 v1 = rowp[1];
    float4 v2 = rowp[2];
    float4 v3 = rowp[3];

    float sA = dot4(v0, ka[0]) + dot4(v1, ka[1]) + dot4(v2, ka[2]) + dot4(v3, ka[3]);
    float sB = dot4(v0, kb[0]) + dot4(v1, kb[1]) + dot4(v2, kb[2]) + dot4(v3, kb[3]);
    float sC = dot4(v0, kc[0]) + dot4(v1, kc[1]) + dot4(v2, kc[2]) + dot4(v3, kc[3]);

    sA += __shfl_xor(sA, 1); sA += __shfl_xor(sA, 2);
    sB += __shfl_xor(sB, 1); sB += __shfl_xor(sB, 2);
    sC += __shfl_xor(sC, 1); sC += __shfl_xor(sC, 2);

    if (sA > bsA) { bsA = sA; biA = r; }
    if (sB > bsB) { bsB = sB; biB = r; }
    if (sC > bsC) { bsC = sC; biC = r; }
  }

  // pack: high 32 = sortable score key, low 32 = ~idx (ties -> smallest idx wins max)
  unsigned long long p0 = ((unsigned long long)fkey(bsA) << 32) | (unsigned long long)(0xFFFFFFFFu - (unsigned)biA);
  unsigned long long p1 = ((unsigned long long)fkey(bsB) << 32) | (unsigned long long)(0xFFFFFFFFu - (unsigned)biB);
  unsigned long long p2 = ((unsigned long long)fkey(bsC) << 32) | (unsigned long long)(0xFFFFFFFFu - (unsigned)biC);
#pragma unroll
  for (int m = 4; m < 64; m <<= 1) {   // lanes within 4-group already identical; start at 4
    unsigned long long t;
    t = __shfl_xor(p0, m); if (t > p0) p0 = t;
    t = __shfl_xor(p1, m); if (t > p1) p1 = t;
    t = __shfl_xor(p2, m); if (t > p2) p2 = t;
  }
  __shared__ unsigned long long red[3][4];
  int wv = tid >> 6;
  if ((tid & 63) == 0) { red[0][wv] = p0; red[1][wv] = p1; red[2][wv] = p2; }
  __syncthreads();
  if (tid == 0) {
#pragma unroll
    for (int h = 0; h < 3; ++h) {
      if (h >= nh) break;
      unsigned long long m0 = red[h][0];
      for (int w = 1; w < 4; ++w) if (red[h][w] > m0) m0 = red[h][w];
      atomicMax(&packed[h0 + h], m0);
    }
  }
}

// ---- kernel 3: decode winners, compute 12 value dots, write all 32 outputs
__global__ void epi_kernel(const float* __restrict__ prog, const float* __restrict__ stck,
                           const float* __restrict__ locl, const float* __restrict__ heap,
                           const float* __restrict__ call,
                           const float* __restrict__ WV1, const float* __restrict__ WVc,
                           const float* __restrict__ ws, float* __restrict__ out) {
  const unsigned long long* packed = (const unsigned long long*)(ws + PACK_OFF);
  __shared__ int sidx[10];
  int tid = threadIdx.x;
  if (tid < 10) {
    unsigned long long p = packed[tid];
    unsigned int key = (unsigned int)(p >> 32);
    int idx = (int)(0xFFFFFFFFu - (unsigned int)(p & 0xFFFFFFFFull));
    sidx[tid] = idx;
    out[12 + tid] = funkey(key);        // best_scores
    out[22 + tid] = (float)idx;         // best_idx (as f32)
  }
  __syncthreads();
  int p = tid >> 4, l = tid & 15;
  if (p < 12) {
    int hh = (p < 9) ? p : 9;
    const float* wrow = (p < 9) ? (WV1 + p * 64) : (WVc + (p - 9) * 64);
    const float* mem;
    if (hh < 2) mem = prog;
    else if (hh < 5) mem = stck;
    else if (hh < 7) mem = locl;
    else if (hh < 9) mem = heap;
    else mem = call;
    const float* row = mem + (size_t)sidx[hh] * 64;
    float s = 0.f;
#pragma unroll
    for (int j = 0; j < 4; ++j) s += wrow[l * 4 + j] * row[l * 4 + j];
#pragma unroll
    for (int m = 1; m < 16; m <<= 1) s += __shfl_xor(s, m);
    if (l == 0) out[p] = s;
  }
}

extern "C" void kernel_launch(void* const* d_in, const int* in_sizes, int n_in,
                              void* d_out, int out_size, void* d_ws, size_t ws_size,
                              hipStream_t stream) {
  const float* query = (const float*)d_in[0];
  const float* prog  = (const float*)d_in[1];
  const float* stck  = (const float*)d_in[2];
  const float* locl  = (const float*)d_in[3];
  const float* heap  = (const float*)d_in[4];
  const float* call  = (const float*)d_in[5];
  const float* WQ    = (const float*)d_in[6];
  const float* bQ    = (const float*)d_in[7];
  const float* WK    = (const float*)d_in[8];
  const float* WV1   = (const float*)d_in[9];
  const float* WVc   = (const float*)d_in[10];
  float* ws  = (float*)d_ws;
  float* out = (float*)d_out;

  hipLaunchKernelGGL(prep_kernel, dim3(1), dim3(256), 0, stream, query, WQ, bQ, WK, ws);
  hipLaunchKernelGGL(scan_kernel, dim3(1600), dim3(256), 0, stream,
                     prog, stck, locl, heap, call, ws);
  hipLaunchKernelGGL(epi_kernel, dim3(1), dim3(256), 0, stream,
                     prog, stck, locl, heap, call, WV1, WVc, ws, out);
}

// Round 3
// 48.587 us; speedup vs baseline: 1.5404x; 1.3021x over previous
//
#include <hip/hip_runtime.h>
#include <math.h>

// ws layout: floats [0..639] = k_eff (10 heads x 64)
// from byte 2560 (float offset 640): 6784 x u64 per-block packed results,
// grouped per head at fixed offsets (see HOFF/HCNT).
#define PACK_OFF 640

// per-head result-array offsets (in u64) and entry counts
// prog: 1024 blocks (heads 0,1) | stck: 512 (2,3,4) | locl: 512 (5,6)
// heap: 1024 (7,8) | call: 128 (9)
__device__ __constant__ int HOFF[10] = {0, 1024, 2048, 2560, 3072, 3584, 4096, 4608, 5632, 6656};
__device__ __constant__ int HCNT[10] = {1024, 1024, 512, 512, 512, 512, 512, 1024, 1024, 128};

__device__ __forceinline__ unsigned int fkey(float f) {
  unsigned int u = __float_as_uint(f);
  return (u & 0x80000000u) ? ~u : (u | 0x80000000u);
}
__device__ __forceinline__ float funkey(unsigned int k) {
  unsigned int u = (k & 0x80000000u) ? (k & 0x7fffffffu) : ~k;
  return __uint_as_float(u);
}
__device__ __forceinline__ float dot4(float4 a, float4 b) {
  return a.x * b.x + a.y * b.y + a.z * b.z + a.w * b.w;
}

// ---- kernel 1: q = WQ@query + bQ ; k_eff[h] = q[h,0]*WK[h,0] + q[h,1]*WK[h,1]
__global__ void prep_kernel(const float* __restrict__ query,
                            const float* __restrict__ WQ,
                            const float* __restrict__ bQ,
                            const float* __restrict__ WK,
                            float* __restrict__ ws) {
  __shared__ float q[20];
  int tid = threadIdx.x;
  if (tid < 20) {
    const float* w = WQ + tid * 64;   // WQ[h][t][:] with tid = h*2+t
    float s = bQ[tid];
    for (int d = 0; d < 64; ++d) s += w[d] * query[d];
    q[tid] = s;
  }
  __syncthreads();
  for (int i = tid; i < 640; i += 256) {
    int h = i >> 6, d = i & 63;
    ws[i] = q[h * 2] * WK[h * 128 + d] + q[h * 2 + 1] * WK[h * 128 + 64 + d];
  }
}

// ---- kernel 2: scan all banks; 4 lanes per row; 256 rows per block;
//      per-block winners written NON-atomically to per-head arrays in ws.
__global__ __launch_bounds__(256) void scan_kernel(
    const float* __restrict__ prog, const float* __restrict__ stck,
    const float* __restrict__ locl, const float* __restrict__ heap,
    const float* __restrict__ call, float* __restrict__ ws) {
  const float* keff = ws;
  unsigned long long* res = (unsigned long long*)(ws + PACK_OFF);

  int b = blockIdx.x;
  const float* mem; int h0, nh, brank;
  int off0, off1, off2;
  if (b < 1024)      { mem = prog; h0 = 0; nh = 2; brank = b;
                       off0 = 0 + brank;    off1 = 1024 + brank; off2 = 0; }
  else if (b < 1536) { mem = stck; h0 = 2; nh = 3; brank = b - 1024;
                       off0 = 2048 + brank; off1 = 2560 + brank; off2 = 3072 + brank; }
  else if (b < 2048) { mem = locl; h0 = 5; nh = 2; brank = b - 1536;
                       off0 = 3584 + brank; off1 = 4096 + brank; off2 = 0; }
  else if (b < 3072) { mem = heap; h0 = 7; nh = 2; brank = b - 2048;
                       off0 = 4608 + brank; off1 = 5632 + brank; off2 = 0; }
  else               { mem = call; h0 = 9; nh = 1; brank = b - 3072;
                       off0 = 6656 + brank; off1 = 0;            off2 = 0; }
  // every block: contiguous 256-row chunk, 4 iterations x 64 rows

  int tid = threadIdx.x;
  int lane4 = tid & 3;     // column group: 16 consecutive floats
  int rsub = tid >> 2;     // row within 64-row sub-chunk

  float4 z = make_float4(0.f, 0.f, 0.f, 0.f);
  float4 ka[4], kb[4], kc[4];
#pragma unroll
  for (int j = 0; j < 4; ++j) {
    ka[j] = ((const float4*)(keff + (h0 + 0) * 64 + lane4 * 16))[j];
    kb[j] = (nh > 1) ? ((const float4*)(keff + (h0 + 1) * 64 + lane4 * 16))[j] : z;
    kc[j] = (nh > 2) ? ((const float4*)(keff + (h0 + 2) * 64 + lane4 * 16))[j] : z;
  }

  float bsA = -INFINITY, bsB = -INFINITY, bsC = -INFINITY;
  int biA = 0, biB = 0, biC = 0;

  int base = b < 3072 ? brank * 256 : brank * 256; // uniform 256 rows/block
  base = brank * 256;
#pragma unroll 2
  for (int it = 0; it < 4; ++it) {
    int r = base + it * 64 + rsub;
    const float4* rowp = (const float4*)(mem + (size_t)r * 64 + lane4 * 16);
    float4 v0 = rowp[0];
    float4 v1 = rowp[1];
    float4 v2 = rowp[2];
    float4 v3 = rowp[3];

    float sA = dot4(v0, ka[0]) + dot4(v1, ka[1]) + dot4(v2, ka[2]) + dot4(v3, ka[3]);
    float sB = dot4(v0, kb[0]) + dot4(v1, kb[1]) + dot4(v2, kb[2]) + dot4(v3, kb[3]);
    float sC = dot4(v0, kc[0]) + dot4(v1, kc[1]) + dot4(v2, kc[2]) + dot4(v3, kc[3]);

    sA += __shfl_xor(sA, 1); sA += __shfl_xor(sA, 2);
    sB += __shfl_xor(sB, 1); sB += __shfl_xor(sB, 2);
    sC += __shfl_xor(sC, 1); sC += __shfl_xor(sC, 2);

    if (sA > bsA) { bsA = sA; biA = r; }
    if (sB > bsB) { bsB = sB; biB = r; }
    if (sC > bsC) { bsC = sC; biC = r; }
  }

  // pack: high 32 = sortable score key, low 32 = ~idx (ties -> smallest idx wins max)
  unsigned long long p0 = ((unsigned long long)fkey(bsA) << 32) | (unsigned long long)(0xFFFFFFFFu - (unsigned)biA);
  unsigned long long p1 = ((unsigned long long)fkey(bsB) << 32) | (unsigned long long)(0xFFFFFFFFu - (unsigned)biB);
  unsigned long long p2 = ((unsigned long long)fkey(bsC) << 32) | (unsigned long long)(0xFFFFFFFFu - (unsigned)biC);
#pragma unroll
  for (int m = 4; m < 64; m <<= 1) {   // lanes within 4-group already identical; start at 4
    unsigned long long t;
    t = __shfl_xor(p0, m); if (t > p0) p0 = t;
    t = __shfl_xor(p1, m); if (t > p1) p1 = t;
    t = __shfl_xor(p2, m); if (t > p2) p2 = t;
  }
  __shared__ unsigned long long red[3][4];
  int wv = tid >> 6;
  if ((tid & 63) == 0) { red[0][wv] = p0; red[1][wv] = p1; red[2][wv] = p2; }
  __syncthreads();
  if (tid == 0) {
    unsigned long long m0 = red[0][0], m1 = red[1][0], m2 = red[2][0];
#pragma unroll
    for (int w = 1; w < 4; ++w) {
      if (red[0][w] > m0) m0 = red[0][w];
      if (red[1][w] > m1) m1 = red[1][w];
      if (red[2][w] > m2) m2 = red[2][w];
    }
    res[off0] = m0;
    if (nh > 1) res[off1] = m1;
    if (nh > 2) res[off2] = m2;
  }
}

// ---- kernel 3: reduce per-head arrays (1 wave per head), then 12 value dots.
__global__ __launch_bounds__(640) void epi_kernel(
    const float* __restrict__ prog, const float* __restrict__ stck,
    const float* __restrict__ locl, const float* __restrict__ heap,
    const float* __restrict__ call,
    const float* __restrict__ WV1, const float* __restrict__ WVc,
    const float* __restrict__ ws, float* __restrict__ out) {
  const unsigned long long* res = (const unsigned long long*)(ws + PACK_OFF);
  __shared__ int sidx[10];
  int tid = threadIdx.x;
  int w = tid >> 6, lane = tid & 63;
  if (w < 10) {
    const unsigned long long* base = res + HOFF[w];
    int n = HCNT[w];
    unsigned long long m = 0ull;
    for (int i = lane; i < n; i += 64) {
      unsigned long long v = base[i];
      if (v > m) m = v;
    }
#pragma unroll
    for (int s = 1; s < 64; s <<= 1) {
      unsigned long long t = __shfl_xor(m, s);
      if (t > m) m = t;
    }
    if (lane == 0) {
      unsigned int key = (unsigned int)(m >> 32);
      int idx = (int)(0xFFFFFFFFu - (unsigned int)(m & 0xFFFFFFFFull));
      sidx[w] = idx;
      out[12 + w] = funkey(key);      // best_scores
      out[22 + w] = (float)idx;       // best_idx (as f32)
    }
  }
  __syncthreads();
  int p = tid >> 4, l = tid & 15;
  if (p < 12) {
    int hh = (p < 9) ? p : 9;
    const float* wrow = (p < 9) ? (WV1 + p * 64) : (WVc + (p - 9) * 64);
    const float* mem;
    if (hh < 2) mem = prog;
    else if (hh < 5) mem = stck;
    else if (hh < 7) mem = locl;
    else if (hh < 9) mem = heap;
    else mem = call;
    const float* row = mem + (size_t)sidx[hh] * 64;
    float s = 0.f;
#pragma unroll
    for (int j = 0; j < 4; ++j) s += wrow[l * 4 + j] * row[l * 4 + j];
#pragma unroll
    for (int m = 1; m < 16; m <<= 1) s += __shfl_xor(s, m);
    if (l == 0) out[p] = s;
  }
}

extern "C" void kernel_launch(void* const* d_in, const int* in_sizes, int n_in,
                              void* d_out, int out_size, void* d_ws, size_t ws_size,
                              hipStream_t stream) {
  const float* query = (const float*)d_in[0];
  const float* prog  = (const float*)d_in[1];
  const float* stck  = (const float*)d_in[2];
  const float* locl  = (const float*)d_in[3];
  const float* heap  = (const float*)d_in[4];
  const float* call  = (const float*)d_in[5];
  const float* WQ    = (const float*)d_in[6];
  const float* bQ    = (const float*)d_in[7];
  const float* WK    = (const float*)d_in[8];
  const float* WV1   = (const float*)d_in[9];
  const float* WVc   = (const float*)d_in[10];
  float* ws  = (float*)d_ws;
  float* out = (float*)d_out;

  hipLaunchKernelGGL(prep_kernel, dim3(1), dim3(256), 0, stream, query, WQ, bQ, WK, ws);
  hipLaunchKernelGGL(scan_kernel, dim3(3200), dim3(256), 0, stream,
                     prog, stck, locl, heap, call, ws);
  hipLaunchKernelGGL(epi_kernel, dim3(1), dim3(640), 0, stream,
                     prog, stck, locl, heap, call, WV1, WVc, ws, out);
}

// Round 5
// 47.331 us; speedup vs baseline: 1.5812x; 1.0265x over previous
//
#include <hip/hip_runtime.h>
#include <math.h>

// grid layout: 1600 blocks, each owns a contiguous 512-row chunk.
// prog 512 blocks (heads 0,1) | stck 256 (2,3,4) | locl 256 (5,6)
// heap 512 (7,8) | call 64 (9)
// ws: 3392 x u64 per-(block,head) packed winners, grouped per head.
__device__ __constant__ int HOFF[10] = {0, 512, 1024, 1280, 1536, 1792, 2048, 2304, 2816, 3328};
__device__ __constant__ int HCNT[10] = {512, 512, 256, 256, 256, 256, 256, 512, 512, 64};

static __device__ __forceinline__ unsigned int fkey(float f) {
  unsigned int u = __float_as_uint(f);
  return (u & 0x80000000u) ? ~u : (u | 0x80000000u);
}
static __device__ __forceinline__ float funkey(unsigned int k) {
  unsigned int u = (k & 0x80000000u) ? (k & 0x7fffffffu) : ~k;
  return __uint_as_float(u);
}
static __device__ __forceinline__ float dot4(float4 a, float4 b) {
  return a.x * b.x + a.y * b.y + a.z * b.z + a.w * b.w;
}

// ---- kernel 1: per-block prep (q + k_eff in LDS) + scan + block-winner store.
__global__ __launch_bounds__(256) void scan_kernel(
    const float* __restrict__ query,
    const float* __restrict__ prog, const float* __restrict__ stck,
    const float* __restrict__ locl, const float* __restrict__ heap,
    const float* __restrict__ call,
    const float* __restrict__ WQ, const float* __restrict__ bQ,
    const float* __restrict__ WK, float* __restrict__ ws)
{
  unsigned long long* res = (unsigned long long*)ws;
  int b = blockIdx.x, tid = threadIdx.x;

  const float* mem; int h0, nh, brank, off0, off1, off2;
  if (b < 512)       { mem = prog; h0 = 0; nh = 2; brank = b;        off0 = 0    + brank; off1 = 512  + brank; off2 = 0; }
  else if (b < 768)  { mem = stck; h0 = 2; nh = 3; brank = b - 512;  off0 = 1024 + brank; off1 = 1280 + brank; off2 = 1536 + brank; }
  else if (b < 1024) { mem = locl; h0 = 5; nh = 2; brank = b - 768;  off0 = 1792 + brank; off1 = 2048 + brank; off2 = 0; }
  else if (b < 1536) { mem = heap; h0 = 7; nh = 2; brank = b - 1024; off0 = 2304 + brank; off1 = 2816 + brank; off2 = 0; }
  else               { mem = call; h0 = 9; nh = 1; brank = b - 1536; off0 = 3328 + brank; off1 = 0;            off2 = 0; }

  // ---- phase 0: q (serial 64-dot, bitwise-identical to reference) + k_eff in LDS
  __shared__ float qs[6];
  __shared__ float skeff[3][64];
  if (tid < 2 * nh) {
    int t = tid; // row index into this block's heads: head h0 + (t>>1), term t&1
    const float* wq = WQ + (h0 * 2 + t) * 64;
    float s = bQ[h0 * 2 + t];
    for (int d = 0; d < 64; ++d) s += wq[d] * query[d];
    qs[t] = s;
  }
  __syncthreads();
  if (tid < 192) {
    int i = tid >> 6, d = tid & 63;
    float v = 0.f;
    if (i < nh) {
      int h = h0 + i;
      v = qs[2 * i] * WK[(h * 2) * 64 + d] + qs[2 * i + 1] * WK[(h * 2 + 1) * 64 + d];
    }
    skeff[i][d] = v;
  }
  __syncthreads();

  // ---- phase 1: scan 512 rows. 4 lanes per row; each load instruction covers
  // 16 FULL 64B cache lines (lanes 0-3 contiguous within a line).
  int lane4 = tid & 3, rsub = tid >> 2;

  float4 ka[4], kb[4], kc[4];
#pragma unroll
  for (int j = 0; j < 4; ++j) {
    ka[j] = ((const float4*)skeff[0])[j * 4 + lane4];
    kb[j] = ((const float4*)skeff[1])[j * 4 + lane4];
    kc[j] = ((const float4*)skeff[2])[j * 4 + lane4];
  }

  float bsA = -INFINITY, bsB = -INFINITY, bsC = -INFINITY;
  int biA = 0, biB = 0, biC = 0;
  int base = brank * 512;
#pragma unroll 2
  for (int it = 0; it < 8; ++it) {
    int r = base + it * 64 + rsub;
    const float* rowp = mem + (size_t)r * 64 + lane4 * 4;
    float4 v0 = *(const float4*)(rowp +  0);  // floats lane4*4 +  0.. 3
    float4 v1 = *(const float4*)(rowp + 16);  // floats lane4*4 + 16..19
    float4 v2 = *(const float4*)(rowp + 32);
    float4 v3 = *(const float4*)(rowp + 48);

    float sA = dot4(v0, ka[0]) + dot4(v1, ka[1]) + dot4(v2, ka[2]) + dot4(v3, ka[3]);
    float sB = dot4(v0, kb[0]) + dot4(v1, kb[1]) + dot4(v2, kb[2]) + dot4(v3, kb[3]);
    float sC = dot4(v0, kc[0]) + dot4(v1, kc[1]) + dot4(v2, kc[2]) + dot4(v3, kc[3]);

    sA += __shfl_xor(sA, 1); sA += __shfl_xor(sA, 2);
    sB += __shfl_xor(sB, 1); sB += __shfl_xor(sB, 2);
    sC += __shfl_xor(sC, 1); sC += __shfl_xor(sC, 2);

    if (sA > bsA) { bsA = sA; biA = r; }
    if (sB > bsB) { bsB = sB; biB = r; }
    if (sC > bsC) { bsC = sC; biC = r; }
  }

  // ---- phase 2: block reduce, non-atomic store of packed (key, ~idx)
  unsigned long long p0 = ((unsigned long long)fkey(bsA) << 32) | (unsigned long long)(0xFFFFFFFFu - (unsigned)biA);
  unsigned long long p1 = ((unsigned long long)fkey(bsB) << 32) | (unsigned long long)(0xFFFFFFFFu - (unsigned)biB);
  unsigned long long p2 = ((unsigned long long)fkey(bsC) << 32) | (unsigned long long)(0xFFFFFFFFu - (unsigned)biC);
#pragma unroll
  for (int m = 4; m < 64; m <<= 1) {   // lanes within 4-group already identical
    unsigned long long t;
    t = __shfl_xor(p0, m); if (t > p0) p0 = t;
    t = __shfl_xor(p1, m); if (t > p1) p1 = t;
    t = __shfl_xor(p2, m); if (t > p2) p2 = t;
  }
  __shared__ unsigned long long red[3][4];
  int wv = tid >> 6;
  if ((tid & 63) == 0) { red[0][wv] = p0; red[1][wv] = p1; red[2][wv] = p2; }
  __syncthreads();
  if (tid == 0) {
    unsigned long long m0 = red[0][0], m1 = red[1][0], m2 = red[2][0];
#pragma unroll
    for (int w = 1; w < 4; ++w) {
      if (red[0][w] > m0) m0 = red[0][w];
      if (red[1][w] > m1) m1 = red[1][w];
      if (red[2][w] > m2) m2 = red[2][w];
    }
    res[off0] = m0;
    if (nh > 1) res[off1] = m1;
    if (nh > 2) res[off2] = m2;
  }
}

// ---- kernel 2: reduce per-head winner arrays (1 wave per head), then 12 value dots.
__global__ __launch_bounds__(640) void epi_kernel(
    const float* __restrict__ prog, const float* __restrict__ stck,
    const float* __restrict__ locl, const float* __restrict__ heap,
    const float* __restrict__ call,
    const float* __restrict__ WV1, const float* __restrict__ WVc,
    const float* __restrict__ ws, float* __restrict__ out) {
  const unsigned long long* res = (const unsigned long long*)ws;
  __shared__ int sidx[10];
  int tid = threadIdx.x;
  int w = tid >> 6, lane = tid & 63;
  if (w < 10) {
    const unsigned long long* basep = res + HOFF[w];
    int n = HCNT[w];
    unsigned long long m = 0ull;
    for (int i = lane; i < n; i += 64) {
      unsigned long long v = basep[i];
      if (v > m) m = v;
    }
#pragma unroll
    for (int s = 1; s < 64; s <<= 1) {
      unsigned long long t = __shfl_xor(m, s);
      if (t > m) m = t;
    }
    if (lane == 0) {
      unsigned int key = (unsigned int)(m >> 32);
      int idx = (int)(0xFFFFFFFFu - (unsigned int)(m & 0xFFFFFFFFull));
      sidx[w] = idx;
      out[12 + w] = funkey(key);      // best_scores
      out[22 + w] = (float)idx;       // best_idx (as f32)
    }
  }
  __syncthreads();
  int p = tid >> 4, l = tid & 15;
  if (p < 12) {
    int hh = (p < 9) ? p : 9;
    const float* wrow = (p < 9) ? (WV1 + p * 64) : (WVc + (p - 9) * 64);
    const float* vmem;
    if (hh < 2) vmem = prog;
    else if (hh < 5) vmem = stck;
    else if (hh < 7) vmem = locl;
    else if (hh < 9) vmem = heap;
    else vmem = call;
    const float* row = vmem + (size_t)sidx[hh] * 64;
    float s = 0.f;
#pragma unroll
    for (int j = 0; j < 4; ++j) s += wrow[l * 4 + j] * row[l * 4 + j];
#pragma unroll
    for (int m2 = 1; m2 < 16; m2 <<= 1) s += __shfl_xor(s, m2);
    if (l == 0) out[p] = s;
  }
}

extern "C" void kernel_launch(void* const* d_in, const int* in_sizes, int n_in,
                              void* d_out, int out_size, void* d_ws, size_t ws_size,
                              hipStream_t stream) {
  const float* query = (const float*)d_in[0];
  const float* prog  = (const float*)d_in[1];
  const float* stck  = (const float*)d_in[2];
  const float* locl  = (const float*)d_in[3];
  const float* heap  = (const float*)d_in[4];
  const float* call  = (const float*)d_in[5];
  const float* WQ    = (const float*)d_in[6];
  const float* bQ    = (const float*)d_in[7];
  const float* WK    = (const float*)d_in[8];
  const float* WV1   = (const float*)d_in[9];
  const float* WVc   = (const float*)d_in[10];
  float* ws  = (float*)d_ws;
  float* out = (float*)d_out;

  hipLaunchKernelGGL(scan_kernel, dim3(1600), dim3(256), 0, stream,
                     query, prog, stck, locl, heap, call, WQ, bQ, WK, ws);
  hipLaunchKernelGGL(epi_kernel, dim3(1), dim3(640), 0, stream,
                     prog, stck, locl, heap, call, WV1, WVc, ws, out);
}